// Round 8
// baseline (282.627 us; speedup 1.0000x reference)
//
#include <hip/hip_runtime.h>
#include <hip/hip_bf16.h>

typedef short bf16x4 __attribute__((ext_vector_type(4)));
typedef short bf16x8 __attribute__((ext_vector_type(8)));
typedef float fp32x4 __attribute__((ext_vector_type(4)));

#define MFMA16(a, b, c) __builtin_amdgcn_mfma_f32_16x16x32_bf16(a, b, c, 0, 0, 0)

static __device__ __forceinline__ short f2bf(float f) {
    unsigned int b = __float_as_uint(f);
    b += 0x7fffu + ((b >> 16) & 1u);   // RNE
    return (short)(b >> 16);
}

// v_cvt_pk_bf16_f32: packs 2 fp32 -> 2 bf16 (RNE) in one VALU op.
// Bit-identical to f2bf(lo) | f2bf(hi)<<16 for finite inputs.
static __device__ __forceinline__ unsigned int cvt_pk_bf16(float lo, float hi) {
    unsigned int r;
    asm("v_cvt_pk_bf16_f32 %0, %1, %2" : "=v"(r) : "v"(lo), "v"(hi));
    return r;
}

typedef unsigned int uint2v __attribute__((ext_vector_type(2)));

// ---------------------------------------------------------------------------
// Prepass: W[k][n] fp32 -> WbT[n][k] bf16, for all 4 weight matrices.
// 64x64 tiles via LDS. grid (16,16,4), block 256.
// ---------------------------------------------------------------------------
__global__ __launch_bounds__(256) void transpose_w(
    const float* __restrict__ W0, const float* __restrict__ W1,
    const float* __restrict__ W2, const float* __restrict__ W3,
    short* __restrict__ wbt)
{
    __shared__ short t[64][68];
    const int tid = threadIdx.x;
    const int z = blockIdx.z;
    const float* W = (z == 0) ? W0 : (z == 1) ? W1 : (z == 2) ? W2 : W3;
    short* dst = wbt + (size_t)z * 1024 * 1024;
    const int k0 = blockIdx.x * 64, n0 = blockIdx.y * 64;

#pragma unroll
    for (int p = 0; p < 4; ++p) {
        int c = p * 256 + tid;
        int kr = c >> 4, seg = c & 15;
        fp32x4 f = *(const fp32x4*)&W[(k0 + kr) * 1024 + n0 + seg * 4];
        uint2v u;
        u.x = cvt_pk_bf16(f[0], f[1]);
        u.y = cvt_pk_bf16(f[2], f[3]);
        *(uint2v*)&t[kr][seg * 4] = u;
    }
    __syncthreads();
#pragma unroll
    for (int p = 0; p < 2; ++p) {
        int c = p * 256 + tid;
        int nr = c >> 3, ks = c & 7;
        bf16x8 v;
#pragma unroll
        for (int i = 0; i < 8; ++i) v[i] = t[ks * 8 + i][nr];
        *(bf16x8*)&dst[(n0 + nr) * 1024 + k0 + ks * 8] = v;
    }
}

// ---------------------------------------------------------------------------
// 128x128-tile GEMM: C[4096,1024] = X @ W + bias. W given as WbT[n][k] bf16.
// XFP32: X fp32 (converted during staging via cvt_pk) / else X bf16.
// HEADED: bf16 out in [B,H,S,Dh] layout / else fp32 flat.
// z (from swizzled id) selects among up to 3 (X, bias, out) triples.
//
// XCD-aware bijective swizzle (T1): linearized block id lid is remapped so
// each XCD (lid&7) owns a contiguous chunk of (z, m, n) with n fastest ->
// the 8 n-blocks sharing an X-tile run back-to-back on ONE XCD and hit its
// private L2 instead of each XCD re-fetching the tile. nwg % 8 == 0 ->
// bijective. 4 waves, each 64x64 = 4x4 16x16x32 subtiles. BK=32.
// ---------------------------------------------------------------------------
struct GemmArgs {
    const void* X[3];
    const short* W;          // WbT base (z * 1M offset applied)
    const float* bias[3];
    void* out[3];
};

template <bool XFP32, bool HEADED>
__global__ __launch_bounds__(256) void gemm128(GemmArgs ga)
{
    __shared__ __align__(16) short lds_a[128 * 40];
    __shared__ __align__(16) short lds_b[128 * 40];

    const int tid  = threadIdx.x;
    const int lane = tid & 63;
    const int wv   = tid >> 6;
    const int l15  = lane & 15;
    const int quad = lane >> 4;
    const int wm   = (wv >> 1) * 64;
    const int wn   = (wv & 1) * 64;

    // --- XCD swizzle: lid -> swz -> (z, m0, n0); 256 blocks per z-layer ---
    const int nwg = gridDim.x * gridDim.y * gridDim.z;   // 768 or 256
    const int lid = blockIdx.x + gridDim.x * (blockIdx.y + gridDim.y * blockIdx.z);
    const int swz = (lid & 7) * (nwg >> 3) + (lid >> 3);
    const int z   = swz >> 8;
    const int rem = swz & 255;
    const int m0  = (rem >> 3) * 128;
    const int n0  = (rem & 7) * 128;

    const void*  Xv   = ga.X[z];
    const short* W    = ga.W + (size_t)z * 1024 * 1024;
    const float* bias = ga.bias[z];
    void* outv        = ga.out[z];

    fp32x4 acc[4][4];
#pragma unroll
    for (int i = 0; i < 4; ++i)
#pragma unroll
        for (int j = 0; j < 4; ++j)
#pragma unroll
            for (int r = 0; r < 4; ++r) acc[i][j][r] = 0.f;

    for (int k0 = 0; k0 < 1024; k0 += 32) {
        __syncthreads();
        if (XFP32) {
            const float* X = (const float*)Xv;
#pragma unroll
            for (int p = 0; p < 4; ++p) {
                int c = p * 256 + tid;
                int row = c >> 3, ks = c & 7;
                fp32x4 f = *(const fp32x4*)&X[(m0 + row) * 1024 + k0 + ks * 4];
                uint2v u;
                u.x = cvt_pk_bf16(f[0], f[1]);
                u.y = cvt_pk_bf16(f[2], f[3]);
                *(uint2v*)&lds_a[row * 40 + ks * 4] = u;
            }
        } else {
            const short* X = (const short*)Xv;
#pragma unroll
            for (int p = 0; p < 2; ++p) {
                int c = p * 256 + tid;
                int row = c >> 2, ks = c & 3;
                *(bf16x8*)&lds_a[row * 40 + ks * 8] =
                    *(const bf16x8*)&X[(m0 + row) * 1024 + k0 + ks * 8];
            }
        }
#pragma unroll
        for (int p = 0; p < 2; ++p) {
            int c = p * 256 + tid;
            int row = c >> 2, ks = c & 3;
            *(bf16x8*)&lds_b[row * 40 + ks * 8] =
                *(const bf16x8*)&W[(n0 + row) * 1024 + k0 + ks * 8];
        }
        __syncthreads();

        bf16x8 af[4], bf[4];
#pragma unroll
        for (int i = 0; i < 4; ++i)
            af[i] = *(bf16x8*)&lds_a[(wm + i * 16 + l15) * 40 + quad * 8];
#pragma unroll
        for (int j = 0; j < 4; ++j)
            bf[j] = *(bf16x8*)&lds_b[(wn + j * 16 + l15) * 40 + quad * 8];
#pragma unroll
        for (int i = 0; i < 4; ++i)
#pragma unroll
            for (int j = 0; j < 4; ++j)
                acc[i][j] = MFMA16(af[i], bf[j], acc[i][j]);
    }

#pragma unroll
    for (int i = 0; i < 4; ++i)
#pragma unroll
        for (int j = 0; j < 4; ++j)
#pragma unroll
            for (int r = 0; r < 4; ++r) {
                int row = m0 + wm + i * 16 + quad * 4 + r;
                int col = n0 + wn + j * 16 + l15;
                float v = acc[i][j][r] + bias[col];
                if (HEADED) {
                    int b = row >> 11, s = row & 2047;
                    int h = col >> 6,  dh = col & 63;
                    ((short*)outv)[(((b * 16) + h) * 2048 + s) * 64 + dh] = f2bf(v);
                } else {
                    ((float*)outv)[row * 1024 + col] = v;
                }
            }
}

// ---------------------------------------------------------------------------
// Flash attention, max-free softmax (scores are O(1): exp2 never overflows).
// Grid (16 q-blocks of 128, 32 bh), 4 waves; wave owns 32 q rows (2 q-tiles).
//
// SWAPPED QK^T: compute S^T = mfma(K, Q) so each lane holds the P values for
// its own q-row (q = lane&15) entirely in registers. Lane holds keys
// {16*kc + 4*quad + r}; V^T is staged with key columns permuted by
//   pos(kk) = (kk&32) + ((kk&15)>>2)*8 + ((kk>>4)&1)*4 + (kk&3)
// so the PV MFMA contracts correctly (both operands' k-order permuted
// identically). P -> bf16 via v_cvt_pk_bf16_f32.
//
// K DIRECT FROM GLOBAL: the kf fragment layout is K's native row-major
// layout (wave reads 16 rows x 64 contiguous B, coalesced). K chunk = 8 KB,
// shared by all 4 waves + both CU-resident blocks -> L1-hit; the 16
// q-blocks per bh re-read from L2 (256 KB/bh << 4 MB XCD L2). Deletes
// lds_k, its 2 ds_write_b128 + 8 ds_read_b128 per thread per chunk, and
// their bank conflicts. Only V^T staging remains barrier-protected.
// ---------------------------------------------------------------------------
__global__ __launch_bounds__(256) void attention128(
    const short* __restrict__ q, const short* __restrict__ k,
    const short* __restrict__ v, short* __restrict__ ctx)
{
    __shared__ __align__(16) short lds_vt[64 * 74];      // [dh][perm key]

    const int tid  = threadIdx.x;
    const int lane = tid & 63;
    const int wv   = tid >> 6;
    const int l15  = lane & 15;
    const int quad = lane >> 4;
    const int bh   = blockIdx.y;
    const int q0   = blockIdx.x * 128 + wv * 32;

    const short* qb = q + (size_t)bh * 2048 * 64;
    const short* kb = k + (size_t)bh * 2048 * 64;
    const short* vb = v + (size_t)bh * 2048 * 64;

    // Q fragments: 2 q-tiles x 2 dh-halves (B-operand of swapped QK^T)
    bf16x8 qf[2][2];
#pragma unroll
    for (int qt = 0; qt < 2; ++qt)
#pragma unroll
        for (int h2 = 0; h2 < 2; ++h2)
            qf[qt][h2] = *(const bf16x8*)
                &qb[(q0 + qt * 16 + l15) * 64 + h2 * 32 + quad * 8];

    fp32x4 O[2][4];
    fp32x4 rs4[2];
#pragma unroll
    for (int qt = 0; qt < 2; ++qt) {
#pragma unroll
        for (int g = 0; g < 4; ++g)
#pragma unroll
            for (int r = 0; r < 4; ++r) O[qt][g][r] = 0.f;
#pragma unroll
        for (int r = 0; r < 4; ++r) rs4[qt][r] = 0.f;
    }

    const float SCL2E = 0.125f * 1.44269504088896340736f;

    // V staging geometry: thread covers keys {2*k2, 2*k2+1} x dh seg*8..+7
    const int k2   = tid >> 3;         // 0..31
    const int seg  = tid & 7;
    const int kk0  = k2 * 2;
    const int pos0 = (kk0 & 32) + (((kk0 & 15) >> 2) << 3)
                   + (((kk0 >> 4) & 1) << 2) + (kk0 & 3);   // even

    for (int key0 = 0; key0 < 2048; key0 += 64) {
        __syncthreads();
        // stage V^T [64 dh][64 perm-key] (2 global b128 + 8 ds_write_b32)
        bf16x8 v0 = *(const bf16x8*)&vb[(key0 + kk0) * 64 + seg * 8];
        bf16x8 v1 = *(const bf16x8*)&vb[(key0 + kk0 + 1) * 64 + seg * 8];
#pragma unroll
        for (int i = 0; i < 8; ++i) {
            unsigned int w = (unsigned int)(unsigned short)v0[i]
                           | ((unsigned int)(unsigned short)v1[i] << 16);
            *(unsigned int*)&lds_vt[(seg * 8 + i) * 74 + pos0] = w;
        }
        __syncthreads();

        // K fragments (A-operand) DIRECT from global (L1/L2-resident)
        bf16x8 kf[4][2];
#pragma unroll
        for (int kc = 0; kc < 4; ++kc)
#pragma unroll
            for (int h2 = 0; h2 < 2; ++h2)
                kf[kc][h2] = *(const bf16x8*)
                    &kb[(key0 + kc * 16 + l15) * 64 + h2 * 32 + quad * 8];

        // S^T = K @ Q^T -> exp2 -> P in registers (packed via cvt_pk)
        union { bf16x8 v; unsigned int u[4]; } pfr[2][2];
#pragma unroll
        for (int qt = 0; qt < 2; ++qt) {
#pragma unroll
            for (int kc = 0; kc < 4; ++kc) {
                fp32x4 s;
#pragma unroll
                for (int r = 0; r < 4; ++r) s[r] = 0.f;
                s = MFMA16(kf[kc][0], qf[qt][0], s);
                s = MFMA16(kf[kc][1], qf[qt][1], s);
                fp32x4 p;
#pragma unroll
                for (int r = 0; r < 4; ++r) {
                    p[r] = __builtin_amdgcn_exp2f(s[r] * SCL2E);
                    rs4[qt][r] += p[r];
                }
                pfr[qt][kc >> 1].u[(kc & 1) * 2 + 0] = cvt_pk_bf16(p[0], p[1]);
                pfr[qt][kc >> 1].u[(kc & 1) * 2 + 1] = cvt_pk_bf16(p[2], p[3]);
            }
        }

        // O += P @ V  (V^T columns pre-permuted to match lane-held P order)
#pragma unroll
        for (int g = 0; g < 4; ++g)
#pragma unroll
            for (int ks = 0; ks < 2; ++ks) {
                bf16x8 vf = *(bf16x8*)
                    &lds_vt[(g * 16 + l15) * 74 + ks * 32 + quad * 8];
#pragma unroll
                for (int qt = 0; qt < 2; ++qt)
                    O[qt][g] = MFMA16(pfr[qt][ks].v, vf, O[qt][g]);
            }
    }

    // reduce row sums across quads, normalize, store context
    const int b = bh >> 4, h = bh & 15;
#pragma unroll
    for (int qt = 0; qt < 2; ++qt) {
        float t = (rs4[qt][0] + rs4[qt][1]) + (rs4[qt][2] + rs4[qt][3]);
        t += __shfl_xor(t, 16);
        t += __shfl_xor(t, 32);
        // lanes 0..15 (quad 0) hold the denominator for q-row = l15
#pragma unroll
        for (int r = 0; r < 4; ++r) {
            float tot = __shfl(t, quad * 4 + r);
            float inv = 1.f / tot;
            int qq  = q0 + qt * 16 + quad * 4 + r;
            int row = b * 2048 + qq;
#pragma unroll
            for (int g = 0; g < 4; ++g) {
                int col = h * 64 + g * 16 + l15;
                ctx[row * 1024 + col] = f2bf(O[qt][g][r] * inv);
            }
        }
    }
}

extern "C" void kernel_launch(void* const* d_in, const int* in_sizes, int n_in,
                              void* d_out, int out_size, void* d_ws, size_t ws_size,
                              hipStream_t stream) {
    const float* Q  = (const float*)d_in[0];
    const float* K  = (const float*)d_in[1];
    const float* V  = (const float*)d_in[2];
    const float* Wq = (const float*)d_in[3];
    const float* bq = (const float*)d_in[4];
    const float* Wk = (const float*)d_in[5];
    const float* bk = (const float*)d_in[6];
    const float* Wv = (const float*)d_in[7];
    const float* bv = (const float*)d_in[8];
    const float* Wo = (const float*)d_in[9];
    const float* bo = (const float*)d_in[10];

    const size_t NEL = 4096ull * 1024ull;
    // ws: WbT (4M shorts) | vbuf (4M) | cbuf (4M)  = 24 MB
    short* wbt  = (short*)d_ws;
    short* vbuf = wbt + 4 * 1024 * 1024;
    short* cbuf = vbuf + NEL;
    // q/k bf16 intermediates borrow d_out (consumed before final GEMM writes)
    short* qbuf = (short*)d_out;
    short* kbuf = (short*)d_out + NEL;

    dim3 blk(256);
    hipLaunchKernelGGL(transpose_w, dim3(16, 16, 4), blk, 0, stream,
                       Wq, Wk, Wv, Wo, wbt);

    GemmArgs g1;
    g1.X[0] = Q;  g1.X[1] = K;  g1.X[2] = V;
    g1.W = wbt;
    g1.bias[0] = bq; g1.bias[1] = bk; g1.bias[2] = bv;
    g1.out[0] = qbuf; g1.out[1] = kbuf; g1.out[2] = vbuf;
    hipLaunchKernelGGL((gemm128<true, true>), dim3(8, 32, 3), blk, 0, stream, g1);

    hipLaunchKernelGGL(attention128, dim3(16, 32), blk, 0, stream,
                       qbuf, kbuf, vbuf, cbuf);

    GemmArgs g2;
    g2.X[0] = cbuf; g2.X[1] = cbuf; g2.X[2] = cbuf;
    g2.W = wbt + 3ull * 1024 * 1024;
    g2.bias[0] = bo; g2.bias[1] = bo; g2.bias[2] = bo;
    g2.out[0] = d_out; g2.out[1] = d_out; g2.out[2] = d_out;
    hipLaunchKernelGGL((gemm128<false, false>), dim3(8, 32, 1), blk, 0, stream, g2);
}

// Round 9
// 249.612 us; speedup vs baseline: 1.1323x; 1.1323x over previous
//
#include <hip/hip_runtime.h>
#include <hip/hip_bf16.h>

typedef short bf16x4 __attribute__((ext_vector_type(4)));
typedef short bf16x8 __attribute__((ext_vector_type(8)));
typedef float fp32x4 __attribute__((ext_vector_type(4)));

#define MFMA16(a, b, c) __builtin_amdgcn_mfma_f32_16x16x32_bf16(a, b, c, 0, 0, 0)

static __device__ __forceinline__ short f2bf(float f) {
    unsigned int b = __float_as_uint(f);
    b += 0x7fffu + ((b >> 16) & 1u);   // RNE
    return (short)(b >> 16);
}

// v_cvt_pk_bf16_f32: packs 2 fp32 -> 2 bf16 (RNE) in one VALU op.
static __device__ __forceinline__ unsigned int cvt_pk_bf16(float lo, float hi) {
    unsigned int r;
    asm("v_cvt_pk_bf16_f32 %0, %1, %2" : "=v"(r) : "v"(lo), "v"(hi));
    return r;
}

// async global->LDS, 16B per lane; LDS dest = wave-uniform base + lane*16.
static __device__ __forceinline__ void gload_lds16(const void* g, void* l) {
    __builtin_amdgcn_global_load_lds(
        (const __attribute__((address_space(1))) unsigned int*)g,
        (__attribute__((address_space(3))) unsigned int*)l, 16, 0, 0);
}

typedef unsigned int uint2v __attribute__((ext_vector_type(2)));

// ---------------------------------------------------------------------------
// Prepass: W[k][n] fp32 -> WbT[n][k] bf16, for all 4 weight matrices.
// ---------------------------------------------------------------------------
__global__ __launch_bounds__(256) void transpose_w(
    const float* __restrict__ W0, const float* __restrict__ W1,
    const float* __restrict__ W2, const float* __restrict__ W3,
    short* __restrict__ wbt)
{
    __shared__ short t[64][68];
    const int tid = threadIdx.x;
    const int z = blockIdx.z;
    const float* W = (z == 0) ? W0 : (z == 1) ? W1 : (z == 2) ? W2 : W3;
    short* dst = wbt + (size_t)z * 1024 * 1024;
    const int k0 = blockIdx.x * 64, n0 = blockIdx.y * 64;

#pragma unroll
    for (int p = 0; p < 4; ++p) {
        int c = p * 256 + tid;
        int kr = c >> 4, seg = c & 15;
        fp32x4 f = *(const fp32x4*)&W[(k0 + kr) * 1024 + n0 + seg * 4];
        uint2v u;
        u.x = cvt_pk_bf16(f[0], f[1]);
        u.y = cvt_pk_bf16(f[2], f[3]);
        *(uint2v*)&t[kr][seg * 4] = u;
    }
    __syncthreads();
#pragma unroll
    for (int p = 0; p < 2; ++p) {
        int c = p * 256 + tid;
        int nr = c >> 3, ks = c & 7;
        bf16x8 v;
#pragma unroll
        for (int i = 0; i < 8; ++i) v[i] = t[ks * 8 + i][nr];
        *(bf16x8*)&dst[(n0 + nr) * 1024 + k0 + ks * 8] = v;
    }
}

// ---------------------------------------------------------------------------
// 128x128-tile GEMM: C[4096,1024] = X @ W + bias. W given as WbT[n][k] bf16.
// XFP32: X fp32, manual cvt_pk staging (stride-40 padded LDS).
// else : X bf16, A staged via global_load_lds into linear [128][32] LDS with
//        XOR column swizzle (source col s^=((row>>1)&3); read slot
//        quad^((l15>>1)&3)) -- both-sides involution, bank-uniform reads.
// B always staged via global_load_lds (same swizzle).
// HEADED: bf16 out in [B,H,S,Dh] layout / else fp32 flat.
// XCD-aware bijective swizzle (T1) on block ids; nwg % 8 == 0.
// 4 waves, each 64x64 = 4x4 16x16x32 subtiles. BK=32.
// ---------------------------------------------------------------------------
struct GemmArgs {
    const void* X[3];
    const short* W;          // WbT base (z * 1M offset applied)
    const float* bias[3];
    void* out[3];
};

template <bool XFP32, bool HEADED>
__global__ __launch_bounds__(256) void gemm128(GemmArgs ga)
{
    __shared__ __align__(16) short lds_a[128 * 40];   // stride 40 (XFP32) or 32
    __shared__ __align__(16) short lds_b[128 * 32];   // linear, gload_lds

    const int tid  = threadIdx.x;
    const int lane = tid & 63;
    const int wv   = tid >> 6;
    const int l15  = lane & 15;
    const int quad = lane >> 4;
    const int wm   = (wv >> 1) * 64;
    const int wn   = (wv & 1) * 64;
    const int sread = (quad ^ ((l15 >> 1) & 3)) * 8;   // swizzled read slot

    // --- XCD swizzle: lid -> swz -> (z, m0, n0); 256 blocks per z-layer ---
    const int nwg = gridDim.x * gridDim.y * gridDim.z;   // 768 or 256
    const int lid = blockIdx.x + gridDim.x * (blockIdx.y + gridDim.y * blockIdx.z);
    const int swz = (lid & 7) * (nwg >> 3) + (lid >> 3);
    const int z   = swz >> 8;
    const int rem = swz & 255;
    const int m0  = (rem >> 3) * 128;
    const int n0  = (rem & 7) * 128;

    const void*  Xv   = ga.X[z];
    const short* W    = ga.W + (size_t)z * 1024 * 1024;
    const float* bias = ga.bias[z];
    void* outv        = ga.out[z];

    // per-thread staging indices for gload_lds slots (slot c = row*4 + s)
    // pass p: c = p*256 + tid; row = c>>2, s = c&3, swizzled col = s^((row>>1)&3)
    fp32x4 acc[4][4];
#pragma unroll
    for (int i = 0; i < 4; ++i)
#pragma unroll
        for (int j = 0; j < 4; ++j)
#pragma unroll
            for (int r = 0; r < 4; ++r) acc[i][j][r] = 0.f;

    for (int k0 = 0; k0 < 1024; k0 += 32) {
        __syncthreads();
        if (XFP32) {
            const float* X = (const float*)Xv;
#pragma unroll
            for (int p = 0; p < 4; ++p) {
                int c = p * 256 + tid;
                int row = c >> 3, ks = c & 7;
                fp32x4 f = *(const fp32x4*)&X[(m0 + row) * 1024 + k0 + ks * 4];
                uint2v u;
                u.x = cvt_pk_bf16(f[0], f[1]);
                u.y = cvt_pk_bf16(f[2], f[3]);
                *(uint2v*)&lds_a[row * 40 + ks * 4] = u;
            }
        } else {
            const short* X = (const short*)Xv;
#pragma unroll
            for (int p = 0; p < 2; ++p) {
                int c = p * 256 + tid;
                int row = c >> 2, s = c & 3;
                int sc = s ^ ((row >> 1) & 3);
                gload_lds16(&X[(m0 + row) * 1024 + k0 + sc * 8],
                            &lds_a[(p * 256 + wv * 64) * 8]);
            }
        }
#pragma unroll
        for (int p = 0; p < 2; ++p) {
            int c = p * 256 + tid;
            int row = c >> 2, s = c & 3;
            int sc = s ^ ((row >> 1) & 3);
            gload_lds16(&W[(n0 + row) * 1024 + k0 + sc * 8],
                        &lds_b[(p * 256 + wv * 64) * 8]);
        }
        __syncthreads();

        bf16x8 af[4], bf[4];
#pragma unroll
        for (int i = 0; i < 4; ++i)
            af[i] = XFP32
                ? *(bf16x8*)&lds_a[(wm + i * 16 + l15) * 40 + quad * 8]
                : *(bf16x8*)&lds_a[(wm + i * 16 + l15) * 32 + sread];
#pragma unroll
        for (int j = 0; j < 4; ++j)
            bf[j] = *(bf16x8*)&lds_b[(wn + j * 16 + l15) * 32 + sread];
#pragma unroll
        for (int i = 0; i < 4; ++i)
#pragma unroll
            for (int j = 0; j < 4; ++j)
                acc[i][j] = MFMA16(af[i], bf[j], acc[i][j]);
    }

#pragma unroll
    for (int i = 0; i < 4; ++i)
#pragma unroll
        for (int j = 0; j < 4; ++j)
#pragma unroll
            for (int r = 0; r < 4; ++r) {
                int row = m0 + wm + i * 16 + quad * 4 + r;
                int col = n0 + wn + j * 16 + l15;
                float v = acc[i][j][r] + bias[col];
                if (HEADED) {
                    int b = row >> 11, s = row & 2047;
                    int h = col >> 6,  dh = col & 63;
                    ((short*)outv)[(((b * 16) + h) * 2048 + s) * 64 + dh] = f2bf(v);
                } else {
                    ((float*)outv)[row * 1024 + col] = v;
                }
            }
}

// ---------------------------------------------------------------------------
// Flash attention (R7 version — best measured). Max-free softmax; swapped
// QK^T keeps P in registers; V^T staged with permuted key columns:
//   pos(kk) = (kk&32) + ((kk&15)>>2)*8 + ((kk>>4)&1)*4 + (kk&3)
// K staged in LDS (ds-read latency beats exposed global latency, R8 lesson).
// P -> bf16 via v_cvt_pk_bf16_f32.
// ---------------------------------------------------------------------------
__global__ __launch_bounds__(256) void attention128(
    const short* __restrict__ q, const short* __restrict__ k,
    const short* __restrict__ v, short* __restrict__ ctx)
{
    __shared__ __align__(16) short lds_k[64 * 74];       // [key][dh]
    __shared__ __align__(16) short lds_vt[64 * 74];      // [dh][perm key]

    const int tid  = threadIdx.x;
    const int lane = tid & 63;
    const int wv   = tid >> 6;
    const int l15  = lane & 15;
    const int quad = lane >> 4;
    const int bh   = blockIdx.y;
    const int q0   = blockIdx.x * 128 + wv * 32;

    const short* qb = q + (size_t)bh * 2048 * 64;
    const short* kb = k + (size_t)bh * 2048 * 64;
    const short* vb = v + (size_t)bh * 2048 * 64;

    bf16x8 qf[2][2];
#pragma unroll
    for (int qt = 0; qt < 2; ++qt)
#pragma unroll
        for (int h2 = 0; h2 < 2; ++h2)
            qf[qt][h2] = *(const bf16x8*)
                &qb[(q0 + qt * 16 + l15) * 64 + h2 * 32 + quad * 8];

    fp32x4 O[2][4];
    fp32x4 rs4[2];
#pragma unroll
    for (int qt = 0; qt < 2; ++qt) {
#pragma unroll
        for (int g = 0; g < 4; ++g)
#pragma unroll
            for (int r = 0; r < 4; ++r) O[qt][g][r] = 0.f;
#pragma unroll
        for (int r = 0; r < 4; ++r) rs4[qt][r] = 0.f;
    }

    const float SCL2E = 0.125f * 1.44269504088896340736f;

    const int k2   = tid >> 3;
    const int seg  = tid & 7;
    const int kk0  = k2 * 2;
    const int pos0 = (kk0 & 32) + (((kk0 & 15) >> 2) << 3)
                   + (((kk0 >> 4) & 1) << 2) + (kk0 & 3);   // even

    const int krow = tid >> 3;
    const int kseg = tid & 7;

    for (int key0 = 0; key0 < 2048; key0 += 64) {
        __syncthreads();
        *(bf16x8*)&lds_k[krow * 74 + kseg * 8] =
            *(const bf16x8*)&kb[(key0 + krow) * 64 + kseg * 8];
        *(bf16x8*)&lds_k[(krow + 32) * 74 + kseg * 8] =
            *(const bf16x8*)&kb[(key0 + krow + 32) * 64 + kseg * 8];
        bf16x8 v0 = *(const bf16x8*)&vb[(key0 + kk0) * 64 + seg * 8];
        bf16x8 v1 = *(const bf16x8*)&vb[(key0 + kk0 + 1) * 64 + seg * 8];
#pragma unroll
        for (int i = 0; i < 8; ++i) {
            unsigned int w = (unsigned int)(unsigned short)v0[i]
                           | ((unsigned int)(unsigned short)v1[i] << 16);
            *(unsigned int*)&lds_vt[(seg * 8 + i) * 74 + pos0] = w;
        }
        __syncthreads();

        bf16x8 kf[4][2];
#pragma unroll
        for (int kc = 0; kc < 4; ++kc)
#pragma unroll
            for (int h2 = 0; h2 < 2; ++h2)
                kf[kc][h2] = *(bf16x8*)
                    &lds_k[(kc * 16 + l15) * 74 + h2 * 32 + quad * 8];

        union { bf16x8 v; unsigned int u[4]; } pfr[2][2];
#pragma unroll
        for (int qt = 0; qt < 2; ++qt) {
#pragma unroll
            for (int kc = 0; kc < 4; ++kc) {
                fp32x4 s;
#pragma unroll
                for (int r = 0; r < 4; ++r) s[r] = 0.f;
                s = MFMA16(kf[kc][0], qf[qt][0], s);
                s = MFMA16(kf[kc][1], qf[qt][1], s);
                fp32x4 p;
#pragma unroll
                for (int r = 0; r < 4; ++r) {
                    p[r] = __builtin_amdgcn_exp2f(s[r] * SCL2E);
                    rs4[qt][r] += p[r];
                }
                pfr[qt][kc >> 1].u[(kc & 1) * 2 + 0] = cvt_pk_bf16(p[0], p[1]);
                pfr[qt][kc >> 1].u[(kc & 1) * 2 + 1] = cvt_pk_bf16(p[2], p[3]);
            }
        }

#pragma unroll
        for (int g = 0; g < 4; ++g)
#pragma unroll
            for (int ks = 0; ks < 2; ++ks) {
                bf16x8 vf = *(bf16x8*)
                    &lds_vt[(g * 16 + l15) * 74 + ks * 32 + quad * 8];
#pragma unroll
                for (int qt = 0; qt < 2; ++qt)
                    O[qt][g] = MFMA16(pfr[qt][ks].v, vf, O[qt][g]);
            }
    }

    const int b = bh >> 4, h = bh & 15;
#pragma unroll
    for (int qt = 0; qt < 2; ++qt) {
        float t = (rs4[qt][0] + rs4[qt][1]) + (rs4[qt][2] + rs4[qt][3]);
        t += __shfl_xor(t, 16);
        t += __shfl_xor(t, 32);
#pragma unroll
        for (int r = 0; r < 4; ++r) {
            float tot = __shfl(t, quad * 4 + r);
            float inv = 1.f / tot;
            int qq  = q0 + qt * 16 + quad * 4 + r;
            int row = b * 2048 + qq;
#pragma unroll
            for (int g = 0; g < 4; ++g) {
                int col = h * 64 + g * 16 + l15;
                ctx[row * 1024 + col] = f2bf(O[qt][g][r] * inv);
            }
        }
    }
}

extern "C" void kernel_launch(void* const* d_in, const int* in_sizes, int n_in,
                              void* d_out, int out_size, void* d_ws, size_t ws_size,
                              hipStream_t stream) {
    const float* Q  = (const float*)d_in[0];
    const float* K  = (const float*)d_in[1];
    const float* V  = (const float*)d_in[2];
    const float* Wq = (const float*)d_in[3];
    const float* bq = (const float*)d_in[4];
    const float* Wk = (const float*)d_in[5];
    const float* bk = (const float*)d_in[6];
    const float* Wv = (const float*)d_in[7];
    const float* bv = (const float*)d_in[8];
    const float* Wo = (const float*)d_in[9];
    const float* bo = (const float*)d_in[10];

    const size_t NEL = 4096ull * 1024ull;
    // ws: WbT (4M shorts) | vbuf (4M) | cbuf (4M)  = 24 MB
    short* wbt  = (short*)d_ws;
    short* vbuf = wbt + 4 * 1024 * 1024;
    short* cbuf = vbuf + NEL;
    // q/k bf16 intermediates borrow d_out (consumed before final GEMM writes)
    short* qbuf = (short*)d_out;
    short* kbuf = (short*)d_out + NEL;

    dim3 blk(256);
    hipLaunchKernelGGL(transpose_w, dim3(16, 16, 4), blk, 0, stream,
                       Wq, Wk, Wv, Wo, wbt);

    GemmArgs g1;
    g1.X[0] = Q;  g1.X[1] = K;  g1.X[2] = V;
    g1.W = wbt;
    g1.bias[0] = bq; g1.bias[1] = bk; g1.bias[2] = bv;
    g1.out[0] = qbuf; g1.out[1] = kbuf; g1.out[2] = vbuf;
    hipLaunchKernelGGL((gemm128<true, true>), dim3(8, 32, 3), blk, 0, stream, g1);

    hipLaunchKernelGGL(attention128, dim3(16, 32), blk, 0, stream,
                       qbuf, kbuf, vbuf, cbuf);

    GemmArgs g2;
    g2.X[0] = cbuf; g2.X[1] = cbuf; g2.X[2] = cbuf;
    g2.W = wbt + 3ull * 1024 * 1024;
    g2.bias[0] = bo; g2.bias[1] = bo; g2.bias[2] = bo;
    g2.out[0] = d_out; g2.out[1] = d_out; g2.out[2] = d_out;
    hipLaunchKernelGGL((gemm128<false, false>), dim3(8, 32, 1), blk, 0, stream, g2);
}

// Round 10
// 247.716 us; speedup vs baseline: 1.1409x; 1.0077x over previous
//
#include <hip/hip_runtime.h>
#include <hip/hip_bf16.h>

typedef short bf16x4 __attribute__((ext_vector_type(4)));
typedef short bf16x8 __attribute__((ext_vector_type(8)));
typedef float fp32x4 __attribute__((ext_vector_type(4)));

#define MFMA16(a, b, c) __builtin_amdgcn_mfma_f32_16x16x32_bf16(a, b, c, 0, 0, 0)

static __device__ __forceinline__ short f2bf(float f) {
    unsigned int b = __float_as_uint(f);
    b += 0x7fffu + ((b >> 16) & 1u);   // RNE
    return (short)(b >> 16);
}

// v_cvt_pk_bf16_f32: packs 2 fp32 -> 2 bf16 (RNE) in one VALU op.
static __device__ __forceinline__ unsigned int cvt_pk_bf16(float lo, float hi) {
    unsigned int r;
    asm("v_cvt_pk_bf16_f32 %0, %1, %2" : "=v"(r) : "v"(lo), "v"(hi));
    return r;
}

// async global->LDS, 16B per lane; LDS dest = wave-uniform base + lane*16.
static __device__ __forceinline__ void gload_lds16(const void* g, void* l) {
    __builtin_amdgcn_global_load_lds(
        (const __attribute__((address_space(1))) unsigned int*)g,
        (__attribute__((address_space(3))) unsigned int*)l, 16, 0, 0);
}

typedef unsigned int uint2v __attribute__((ext_vector_type(2)));

// ---------------------------------------------------------------------------
// Prepass: W[k][n] fp32 -> WbT[n][k] bf16, for all 4 weight matrices.
// ---------------------------------------------------------------------------
__global__ __launch_bounds__(256) void transpose_w(
    const float* __restrict__ W0, const float* __restrict__ W1,
    const float* __restrict__ W2, const float* __restrict__ W3,
    short* __restrict__ wbt)
{
    __shared__ short t[64][68];
    const int tid = threadIdx.x;
    const int z = blockIdx.z;
    const float* W = (z == 0) ? W0 : (z == 1) ? W1 : (z == 2) ? W2 : W3;
    short* dst = wbt + (size_t)z * 1024 * 1024;
    const int k0 = blockIdx.x * 64, n0 = blockIdx.y * 64;

#pragma unroll
    for (int p = 0; p < 4; ++p) {
        int c = p * 256 + tid;
        int kr = c >> 4, seg = c & 15;
        fp32x4 f = *(const fp32x4*)&W[(k0 + kr) * 1024 + n0 + seg * 4];
        uint2v u;
        u.x = cvt_pk_bf16(f[0], f[1]);
        u.y = cvt_pk_bf16(f[2], f[3]);
        *(uint2v*)&t[kr][seg * 4] = u;
    }
    __syncthreads();
#pragma unroll
    for (int p = 0; p < 2; ++p) {
        int c = p * 256 + tid;
        int nr = c >> 3, ks = c & 7;
        bf16x8 v;
#pragma unroll
        for (int i = 0; i < 8; ++i) v[i] = t[ks * 8 + i][nr];
        *(bf16x8*)&dst[(n0 + nr) * 1024 + k0 + ks * 8] = v;
    }
}

// ---------------------------------------------------------------------------
// 128x128-tile GEMM (R9 version): B (and A on bf16 path) staged via
// global_load_lds with both-sides XOR column swizzle; XFP32 A staged
// manually with cvt_pk (stride-40). XCD-aware bijective block swizzle (T1).
// 4 waves, each 64x64 = 4x4 16x16x32 subtiles. BK=32.
// ---------------------------------------------------------------------------
struct GemmArgs {
    const void* X[3];
    const short* W;          // WbT base (z * 1M offset applied)
    const float* bias[3];
    void* out[3];
};

template <bool XFP32, bool HEADED>
__global__ __launch_bounds__(256) void gemm128(GemmArgs ga)
{
    __shared__ __align__(16) short lds_a[128 * 40];   // stride 40 (XFP32) or 32
    __shared__ __align__(16) short lds_b[128 * 32];   // linear, gload_lds

    const int tid  = threadIdx.x;
    const int lane = tid & 63;
    const int wv   = tid >> 6;
    const int l15  = lane & 15;
    const int quad = lane >> 4;
    const int wm   = (wv >> 1) * 64;
    const int wn   = (wv & 1) * 64;
    const int sread = (quad ^ ((l15 >> 1) & 3)) * 8;   // swizzled read slot

    // --- XCD swizzle: lid -> swz -> (z, m0, n0); 256 blocks per z-layer ---
    const int nwg = gridDim.x * gridDim.y * gridDim.z;   // 768 or 256
    const int lid = blockIdx.x + gridDim.x * (blockIdx.y + gridDim.y * blockIdx.z);
    const int swz = (lid & 7) * (nwg >> 3) + (lid >> 3);
    const int z   = swz >> 8;
    const int rem = swz & 255;
    const int m0  = (rem >> 3) * 128;
    const int n0  = (rem & 7) * 128;

    const void*  Xv   = ga.X[z];
    const short* W    = ga.W + (size_t)z * 1024 * 1024;
    const float* bias = ga.bias[z];
    void* outv        = ga.out[z];

    fp32x4 acc[4][4];
#pragma unroll
    for (int i = 0; i < 4; ++i)
#pragma unroll
        for (int j = 0; j < 4; ++j)
#pragma unroll
            for (int r = 0; r < 4; ++r) acc[i][j][r] = 0.f;

    for (int k0 = 0; k0 < 1024; k0 += 32) {
        __syncthreads();
        if (XFP32) {
            const float* X = (const float*)Xv;
#pragma unroll
            for (int p = 0; p < 4; ++p) {
                int c = p * 256 + tid;
                int row = c >> 3, ks = c & 7;
                fp32x4 f = *(const fp32x4*)&X[(m0 + row) * 1024 + k0 + ks * 4];
                uint2v u;
                u.x = cvt_pk_bf16(f[0], f[1]);
                u.y = cvt_pk_bf16(f[2], f[3]);
                *(uint2v*)&lds_a[row * 40 + ks * 4] = u;
            }
        } else {
            const short* X = (const short*)Xv;
#pragma unroll
            for (int p = 0; p < 2; ++p) {
                int c = p * 256 + tid;
                int row = c >> 2, s = c & 3;
                int sc = s ^ ((row >> 1) & 3);
                gload_lds16(&X[(m0 + row) * 1024 + k0 + sc * 8],
                            &lds_a[(p * 256 + wv * 64) * 8]);
            }
        }
#pragma unroll
        for (int p = 0; p < 2; ++p) {
            int c = p * 256 + tid;
            int row = c >> 2, s = c & 3;
            int sc = s ^ ((row >> 1) & 3);
            gload_lds16(&W[(n0 + row) * 1024 + k0 + sc * 8],
                        &lds_b[(p * 256 + wv * 64) * 8]);
        }
        __syncthreads();

        bf16x8 af[4], bf[4];
#pragma unroll
        for (int i = 0; i < 4; ++i)
            af[i] = XFP32
                ? *(bf16x8*)&lds_a[(wm + i * 16 + l15) * 40 + quad * 8]
                : *(bf16x8*)&lds_a[(wm + i * 16 + l15) * 32 + sread];
#pragma unroll
        for (int j = 0; j < 4; ++j)
            bf[j] = *(bf16x8*)&lds_b[(wn + j * 16 + l15) * 32 + sread];
#pragma unroll
        for (int i = 0; i < 4; ++i)
#pragma unroll
            for (int j = 0; j < 4; ++j)
                acc[i][j] = MFMA16(af[i], bf[j], acc[i][j]);
    }

#pragma unroll
    for (int i = 0; i < 4; ++i)
#pragma unroll
        for (int j = 0; j < 4; ++j)
#pragma unroll
            for (int r = 0; r < 4; ++r) {
                int row = m0 + wm + i * 16 + quad * 4 + r;
                int col = n0 + wn + j * 16 + l15;
                float v = acc[i][j][r] + bias[col];
                if (HEADED) {
                    int b = row >> 11, s = row & 2047;
                    int h = col >> 6,  dh = col & 63;
                    ((short*)outv)[(((b * 16) + h) * 2048 + s) * 64 + dh] = f2bf(v);
                } else {
                    ((float*)outv)[row * 1024 + col] = v;
                }
            }
}

// ---------------------------------------------------------------------------
// Flash attention. Max-free softmax; swapped QK^T keeps P in registers;
// V^T staged manually with permuted key columns (pos bijection).
//
// K staged via global_load_lds width=16 into LINEAR [64][64] LDS:
//  - async DMA: no VGPR round-trip, no sync vmcnt wait, 2 fewer ds_writes
//    per thread per chunk; drained by the pre-barrier vmcnt.
//  - linear rows would 16-way-conflict on kf reads (row stride 128B), so
//    16B blocks are XOR-swizzled BOTH sides (rule #21): stored block b' at
//    (row, b') holds global block b'^(row&7); staging lane picks source
//    block (lane&7)^(lane>>3); kf read uses block (h2*4+quad)^(l15&7).
//    Read banks: 8 blocks x 4 dwords = 32 banks, 2-way (free).
// V global loads issued BEFORE K gloads so their vmcnt wait excludes K.
// ---------------------------------------------------------------------------
__global__ __launch_bounds__(256) void attention128(
    const short* __restrict__ q, const short* __restrict__ k,
    const short* __restrict__ v, short* __restrict__ ctx)
{
    __shared__ __align__(16) short lds_k[64 * 64];       // [key][dh] swizzled blocks
    __shared__ __align__(16) short lds_vt[64 * 74];      // [dh][perm key]

    const int tid  = threadIdx.x;
    const int lane = tid & 63;
    const int wv   = tid >> 6;
    const int l15  = lane & 15;
    const int quad = lane >> 4;
    const int bh   = blockIdx.y;
    const int q0   = blockIdx.x * 128 + wv * 32;

    const short* qb = q + (size_t)bh * 2048 * 64;
    const short* kb = k + (size_t)bh * 2048 * 64;
    const short* vb = v + (size_t)bh * 2048 * 64;

    bf16x8 qf[2][2];
#pragma unroll
    for (int qt = 0; qt < 2; ++qt)
#pragma unroll
        for (int h2 = 0; h2 < 2; ++h2)
            qf[qt][h2] = *(const bf16x8*)
                &qb[(q0 + qt * 16 + l15) * 64 + h2 * 32 + quad * 8];

    fp32x4 O[2][4];
    fp32x4 rs4[2];
#pragma unroll
    for (int qt = 0; qt < 2; ++qt) {
#pragma unroll
        for (int g = 0; g < 4; ++g)
#pragma unroll
            for (int r = 0; r < 4; ++r) O[qt][g][r] = 0.f;
#pragma unroll
        for (int r = 0; r < 4; ++r) rs4[qt][r] = 0.f;
    }

    const float SCL2E = 0.125f * 1.44269504088896340736f;

    // V staging geometry: thread covers keys {2*k2, 2*k2+1} x dh seg*8..+7
    const int k2   = tid >> 3;
    const int seg  = tid & 7;
    const int kk0  = k2 * 2;
    const int pos0 = (kk0 & 32) + (((kk0 & 15) >> 2) << 3)
                   + (((kk0 >> 4) & 1) << 2) + (kk0 & 3);   // even

    // K async staging geometry: pass p covers rows p*32 + wv*8 .. +7;
    // lane l -> row offset l>>3, stored block l&7, source block (l&7)^(l>>3)
    const int ksrc  = ((lane & 7) ^ (lane >> 3)) * 8;    // source col (shorts)
    const int krowl = lane >> 3;                         // row within wave seg
    // kf read block index (swizzled): (h2*4+quad) ^ (l15&7)
    const int kswz  = l15 & 7;

    for (int key0 = 0; key0 < 2048; key0 += 64) {
        __syncthreads();
        // V global loads first (their vmcnt wait then excludes K gloads)
        bf16x8 v0 = *(const bf16x8*)&vb[(key0 + kk0) * 64 + seg * 8];
        bf16x8 v1 = *(const bf16x8*)&vb[(key0 + kk0 + 1) * 64 + seg * 8];
        // K async: 2 passes x 1024B per wave, linear dest, swizzled source
#pragma unroll
        for (int p = 0; p < 2; ++p) {
            int row = p * 32 + wv * 8 + krowl;
            gload_lds16(&kb[(key0 + row) * 64 + ksrc],
                        &lds_k[(p * 32 + wv * 8) * 64]);
        }
        // V^T transpose writes
#pragma unroll
        for (int i = 0; i < 8; ++i) {
            unsigned int w = (unsigned int)(unsigned short)v0[i]
                           | ((unsigned int)(unsigned short)v1[i] << 16);
            *(unsigned int*)&lds_vt[(seg * 8 + i) * 74 + pos0] = w;
        }
        __syncthreads();

        bf16x8 kf[4][2];
#pragma unroll
        for (int kc = 0; kc < 4; ++kc)
#pragma unroll
            for (int h2 = 0; h2 < 2; ++h2)
                kf[kc][h2] = *(bf16x8*)
                    &lds_k[(kc * 16 + l15) * 64 + (((h2 * 4 + quad) ^ kswz) * 8)];

        union { bf16x8 v; unsigned int u[4]; } pfr[2][2];
#pragma unroll
        for (int qt = 0; qt < 2; ++qt) {
#pragma unroll
            for (int kc = 0; kc < 4; ++kc) {
                fp32x4 s;
#pragma unroll
                for (int r = 0; r < 4; ++r) s[r] = 0.f;
                s = MFMA16(kf[kc][0], qf[qt][0], s);
                s = MFMA16(kf[kc][1], qf[qt][1], s);
                fp32x4 p;
#pragma unroll
                for (int r = 0; r < 4; ++r) {
                    p[r] = __builtin_amdgcn_exp2f(s[r] * SCL2E);
                    rs4[qt][r] += p[r];
                }
                pfr[qt][kc >> 1].u[(kc & 1) * 2 + 0] = cvt_pk_bf16(p[0], p[1]);
                pfr[qt][kc >> 1].u[(kc & 1) * 2 + 1] = cvt_pk_bf16(p[2], p[3]);
            }
        }

#pragma unroll
        for (int g = 0; g < 4; ++g)
#pragma unroll
            for (int ks = 0; ks < 2; ++ks) {
                bf16x8 vf = *(bf16x8*)
                    &lds_vt[(g * 16 + l15) * 74 + ks * 32 + quad * 8];
#pragma unroll
                for (int qt = 0; qt < 2; ++qt)
                    O[qt][g] = MFMA16(pfr[qt][ks].v, vf, O[qt][g]);
            }
    }

    const int b = bh >> 4, h = bh & 15;
#pragma unroll
    for (int qt = 0; qt < 2; ++qt) {
        float t = (rs4[qt][0] + rs4[qt][1]) + (rs4[qt][2] + rs4[qt][3]);
        t += __shfl_xor(t, 16);
        t += __shfl_xor(t, 32);
#pragma unroll
        for (int r = 0; r < 4; ++r) {
            float tot = __shfl(t, quad * 4 + r);
            float inv = 1.f / tot;
            int qq  = q0 + qt * 16 + quad * 4 + r;
            int row = b * 2048 + qq;
#pragma unroll
            for (int g = 0; g < 4; ++g) {
                int col = h * 64 + g * 16 + l15;
                ctx[row * 1024 + col] = f2bf(O[qt][g][r] * inv);
            }
        }
    }
}

extern "C" void kernel_launch(void* const* d_in, const int* in_sizes, int n_in,
                              void* d_out, int out_size, void* d_ws, size_t ws_size,
                              hipStream_t stream) {
    const float* Q  = (const float*)d_in[0];
    const float* K  = (const float*)d_in[1];
    const float* V  = (const float*)d_in[2];
    const float* Wq = (const float*)d_in[3];
    const float* bq = (const float*)d_in[4];
    const float* Wk = (const float*)d_in[5];
    const float* bk = (const float*)d_in[6];
    const float* Wv = (const float*)d_in[7];
    const float* bv = (const float*)d_in[8];
    const float* Wo = (const float*)d_in[9];
    const float* bo = (const float*)d_in[10];

    const size_t NEL = 4096ull * 1024ull;
    // ws: WbT (4M shorts) | vbuf (4M) | cbuf (4M)  = 24 MB
    short* wbt  = (short*)d_ws;
    short* vbuf = wbt + 4 * 1024 * 1024;
    short* cbuf = vbuf + NEL;
    // q/k bf16 intermediates borrow d_out (consumed before final GEMM writes)
    short* qbuf = (short*)d_out;
    short* kbuf = (short*)d_out + NEL;

    dim3 blk(256);
    hipLaunchKernelGGL(transpose_w, dim3(16, 16, 4), blk, 0, stream,
                       Wq, Wk, Wv, Wo, wbt);

    GemmArgs g1;
    g1.X[0] = Q;  g1.X[1] = K;  g1.X[2] = V;
    g1.W = wbt;
    g1.bias[0] = bq; g1.bias[1] = bk; g1.bias[2] = bv;
    g1.out[0] = qbuf; g1.out[1] = kbuf; g1.out[2] = vbuf;
    hipLaunchKernelGGL((gemm128<true, true>), dim3(8, 32, 3), blk, 0, stream, g1);

    hipLaunchKernelGGL(attention128, dim3(16, 32), blk, 0, stream,
                       qbuf, kbuf, vbuf, cbuf);

    GemmArgs g2;
    g2.X[0] = cbuf; g2.X[1] = cbuf; g2.X[2] = cbuf;
    g2.W = wbt + 3ull * 1024 * 1024;
    g2.bias[0] = bo; g2.bias[1] = bo; g2.bias[2] = bo;
    g2.out[0] = d_out; g2.out[1] = d_out; g2.out[2] = d_out;
    hipLaunchKernelGGL((gemm128<false, false>), dim3(8, 32, 1), blk, 0, stream, g2);
}

// Round 11
// 232.435 us; speedup vs baseline: 1.2159x; 1.0657x over previous
//
#include <hip/hip_runtime.h>
#include <hip/hip_bf16.h>

typedef short bf16x4 __attribute__((ext_vector_type(4)));
typedef short bf16x8 __attribute__((ext_vector_type(8)));
typedef float fp32x4 __attribute__((ext_vector_type(4)));

#define MFMA16(a, b, c) __builtin_amdgcn_mfma_f32_16x16x32_bf16(a, b, c, 0, 0, 0)

static __device__ __forceinline__ short f2bf(float f) {
    unsigned int b = __float_as_uint(f);
    b += 0x7fffu + ((b >> 16) & 1u);   // RNE
    return (short)(b >> 16);
}

// v_cvt_pk_bf16_f32: packs 2 fp32 -> 2 bf16 (RNE) in one VALU op.
static __device__ __forceinline__ unsigned int cvt_pk_bf16(float lo, float hi) {
    unsigned int r;
    asm("v_cvt_pk_bf16_f32 %0, %1, %2" : "=v"(r) : "v"(lo), "v"(hi));
    return r;
}

// async global->LDS, 16B per lane; LDS dest = wave-uniform base + lane*16.
static __device__ __forceinline__ void gload_lds16(const void* g, void* l) {
    __builtin_amdgcn_global_load_lds(
        (const __attribute__((address_space(1))) unsigned int*)g,
        (__attribute__((address_space(3))) unsigned int*)l, 16, 0, 0);
}

typedef unsigned int uint2v __attribute__((ext_vector_type(2)));

// ---------------------------------------------------------------------------
// Prepass: W[k][n] fp32 -> WbT[n][k] bf16, for all 4 weight matrices.
// ---------------------------------------------------------------------------
__global__ __launch_bounds__(256) void transpose_w(
    const float* __restrict__ W0, const float* __restrict__ W1,
    const float* __restrict__ W2, const float* __restrict__ W3,
    short* __restrict__ wbt)
{
    __shared__ short t[64][68];
    const int tid = threadIdx.x;
    const int z = blockIdx.z;
    const float* W = (z == 0) ? W0 : (z == 1) ? W1 : (z == 2) ? W2 : W3;
    short* dst = wbt + (size_t)z * 1024 * 1024;
    const int k0 = blockIdx.x * 64, n0 = blockIdx.y * 64;

#pragma unroll
    for (int p = 0; p < 4; ++p) {
        int c = p * 256 + tid;
        int kr = c >> 4, seg = c & 15;
        fp32x4 f = *(const fp32x4*)&W[(k0 + kr) * 1024 + n0 + seg * 4];
        uint2v u;
        u.x = cvt_pk_bf16(f[0], f[1]);
        u.y = cvt_pk_bf16(f[2], f[3]);
        *(uint2v*)&t[kr][seg * 4] = u;
    }
    __syncthreads();
#pragma unroll
    for (int p = 0; p < 2; ++p) {
        int c = p * 256 + tid;
        int nr = c >> 3, ks = c & 7;
        bf16x8 v;
#pragma unroll
        for (int i = 0; i < 8; ++i) v[i] = t[ks * 8 + i][nr];
        *(bf16x8*)&dst[(n0 + nr) * 1024 + k0 + ks * 8] = v;
    }
}

// ---------------------------------------------------------------------------
// Prepass: X fp32 -> bf16 (RNE via cvt_pk, == f2bf bitwise) for Q, K, V.
// Unlocks the all-async (gload_lds) A-staging path in gemm1.
// Pure BW-bound. grid (512, 3), block 256; 32 elems/thread.
// ---------------------------------------------------------------------------
__global__ __launch_bounds__(256) void convert_x(
    const float* __restrict__ Q, const float* __restrict__ K,
    const float* __restrict__ V,
    short* __restrict__ xq, short* __restrict__ xk, short* __restrict__ xv)
{
    const int z = blockIdx.y;
    const float* src = (z == 0) ? Q : (z == 1) ? K : V;
    short* dst = (z == 0) ? xq : (z == 1) ? xk : xv;
    const int idx = blockIdx.x * 256 + threadIdx.x;   // 0..131071
#pragma unroll
    for (int it = 0; it < 4; ++it) {
        size_t base = ((size_t)it * 131072 + idx) * 8;
        fp32x4 a = *(const fp32x4*)&src[base];
        fp32x4 b = *(const fp32x4*)&src[base + 4];
        uint2v u0, u1;
        u0.x = cvt_pk_bf16(a[0], a[1]);
        u0.y = cvt_pk_bf16(a[2], a[3]);
        u1.x = cvt_pk_bf16(b[0], b[1]);
        u1.y = cvt_pk_bf16(b[2], b[3]);
        *(uint2v*)&dst[base] = u0;
        *(uint2v*)&dst[base + 4] = u1;
    }
}

// ---------------------------------------------------------------------------
// 128x128-tile GEMM: B (and A on bf16 path) staged via global_load_lds with
// both-sides XOR column swizzle; XFP32 A staged manually with cvt_pk
// (stride-40, fallback path). XCD-aware bijective block swizzle (T1).
// 4 waves, each 64x64 = 4x4 16x16x32 subtiles. BK=32.
// ---------------------------------------------------------------------------
struct GemmArgs {
    const void* X[3];
    const short* W;          // WbT base (z * 1M offset applied)
    const float* bias[3];
    void* out[3];
};

template <bool XFP32, bool HEADED>
__global__ __launch_bounds__(256) void gemm128(GemmArgs ga)
{
    __shared__ __align__(16) short lds_a[128 * 40];   // stride 40 (XFP32) or 32
    __shared__ __align__(16) short lds_b[128 * 32];   // linear, gload_lds

    const int tid  = threadIdx.x;
    const int lane = tid & 63;
    const int wv   = tid >> 6;
    const int l15  = lane & 15;
    const int quad = lane >> 4;
    const int wm   = (wv >> 1) * 64;
    const int wn   = (wv & 1) * 64;
    const int sread = (quad ^ ((l15 >> 1) & 3)) * 8;   // swizzled read slot

    // --- XCD swizzle: lid -> swz -> (z, m0, n0); 256 blocks per z-layer ---
    const int nwg = gridDim.x * gridDim.y * gridDim.z;   // 768 or 256
    const int lid = blockIdx.x + gridDim.x * (blockIdx.y + gridDim.y * blockIdx.z);
    const int swz = (lid & 7) * (nwg >> 3) + (lid >> 3);
    const int z   = swz >> 8;
    const int rem = swz & 255;
    const int m0  = (rem >> 3) * 128;
    const int n0  = (rem & 7) * 128;

    const void*  Xv   = ga.X[z];
    const short* W    = ga.W + (size_t)z * 1024 * 1024;
    const float* bias = ga.bias[z];
    void* outv        = ga.out[z];

    fp32x4 acc[4][4];
#pragma unroll
    for (int i = 0; i < 4; ++i)
#pragma unroll
        for (int j = 0; j < 4; ++j)
#pragma unroll
            for (int r = 0; r < 4; ++r) acc[i][j][r] = 0.f;

    for (int k0 = 0; k0 < 1024; k0 += 32) {
        __syncthreads();
        if (XFP32) {
            const float* X = (const float*)Xv;
#pragma unroll
            for (int p = 0; p < 4; ++p) {
                int c = p * 256 + tid;
                int row = c >> 3, ks = c & 7;
                fp32x4 f = *(const fp32x4*)&X[(m0 + row) * 1024 + k0 + ks * 4];
                uint2v u;
                u.x = cvt_pk_bf16(f[0], f[1]);
                u.y = cvt_pk_bf16(f[2], f[3]);
                *(uint2v*)&lds_a[row * 40 + ks * 4] = u;
            }
        } else {
            const short* X = (const short*)Xv;
#pragma unroll
            for (int p = 0; p < 2; ++p) {
                int c = p * 256 + tid;
                int row = c >> 2, s = c & 3;
                int sc = s ^ ((row >> 1) & 3);
                gload_lds16(&X[(m0 + row) * 1024 + k0 + sc * 8],
                            &lds_a[(p * 256 + wv * 64) * 8]);
            }
        }
#pragma unroll
        for (int p = 0; p < 2; ++p) {
            int c = p * 256 + tid;
            int row = c >> 2, s = c & 3;
            int sc = s ^ ((row >> 1) & 3);
            gload_lds16(&W[(n0 + row) * 1024 + k0 + sc * 8],
                        &lds_b[(p * 256 + wv * 64) * 8]);
        }
        __syncthreads();

        bf16x8 af[4], bf[4];
#pragma unroll
        for (int i = 0; i < 4; ++i)
            af[i] = XFP32
                ? *(bf16x8*)&lds_a[(wm + i * 16 + l15) * 40 + quad * 8]
                : *(bf16x8*)&lds_a[(wm + i * 16 + l15) * 32 + sread];
#pragma unroll
        for (int j = 0; j < 4; ++j)
            bf[j] = *(bf16x8*)&lds_b[(wn + j * 16 + l15) * 32 + sread];
#pragma unroll
        for (int i = 0; i < 4; ++i)
#pragma unroll
            for (int j = 0; j < 4; ++j)
                acc[i][j] = MFMA16(af[i], bf[j], acc[i][j]);
    }

#pragma unroll
    for (int i = 0; i < 4; ++i)
#pragma unroll
        for (int j = 0; j < 4; ++j)
#pragma unroll
            for (int r = 0; r < 4; ++r) {
                int row = m0 + wm + i * 16 + quad * 4 + r;
                int col = n0 + wn + j * 16 + l15;
                float v = acc[i][j][r] + bias[col];
                if (HEADED) {
                    int b = row >> 11, s = row & 2047;
                    int h = col >> 6,  dh = col & 63;
                    ((short*)outv)[(((b * 16) + h) * 2048 + s) * 64 + dh] = f2bf(v);
                } else {
                    ((float*)outv)[row * 1024 + col] = v;
                }
            }
}

// ---------------------------------------------------------------------------
// Flash attention (R10 version — best measured). Max-free softmax; swapped
// QK^T keeps P in registers; V^T staged manually with permuted key columns;
// K staged via global_load_lds into linear [64][64] with both-sides 16B-block
// XOR swizzle. V loads issued before K gloads.
// ---------------------------------------------------------------------------
__global__ __launch_bounds__(256) void attention128(
    const short* __restrict__ q, const short* __restrict__ k,
    const short* __restrict__ v, short* __restrict__ ctx)
{
    __shared__ __align__(16) short lds_k[64 * 64];       // [key][dh] swizzled blocks
    __shared__ __align__(16) short lds_vt[64 * 74];      // [dh][perm key]

    const int tid  = threadIdx.x;
    const int lane = tid & 63;
    const int wv   = tid >> 6;
    const int l15  = lane & 15;
    const int quad = lane >> 4;
    const int bh   = blockIdx.y;
    const int q0   = blockIdx.x * 128 + wv * 32;

    const short* qb = q + (size_t)bh * 2048 * 64;
    const short* kb = k + (size_t)bh * 2048 * 64;
    const short* vb = v + (size_t)bh * 2048 * 64;

    bf16x8 qf[2][2];
#pragma unroll
    for (int qt = 0; qt < 2; ++qt)
#pragma unroll
        for (int h2 = 0; h2 < 2; ++h2)
            qf[qt][h2] = *(const bf16x8*)
                &qb[(q0 + qt * 16 + l15) * 64 + h2 * 32 + quad * 8];

    fp32x4 O[2][4];
    fp32x4 rs4[2];
#pragma unroll
    for (int qt = 0; qt < 2; ++qt) {
#pragma unroll
        for (int g = 0; g < 4; ++g)
#pragma unroll
            for (int r = 0; r < 4; ++r) O[qt][g][r] = 0.f;
#pragma unroll
        for (int r = 0; r < 4; ++r) rs4[qt][r] = 0.f;
    }

    const float SCL2E = 0.125f * 1.44269504088896340736f;

    const int k2   = tid >> 3;
    const int seg  = tid & 7;
    const int kk0  = k2 * 2;
    const int pos0 = (kk0 & 32) + (((kk0 & 15) >> 2) << 3)
                   + (((kk0 >> 4) & 1) << 2) + (kk0 & 3);   // even

    const int ksrc  = ((lane & 7) ^ (lane >> 3)) * 8;    // source col (shorts)
    const int krowl = lane >> 3;
    const int kswz  = l15 & 7;

    for (int key0 = 0; key0 < 2048; key0 += 64) {
        __syncthreads();
        bf16x8 v0 = *(const bf16x8*)&vb[(key0 + kk0) * 64 + seg * 8];
        bf16x8 v1 = *(const bf16x8*)&vb[(key0 + kk0 + 1) * 64 + seg * 8];
#pragma unroll
        for (int p = 0; p < 2; ++p) {
            int row = p * 32 + wv * 8 + krowl;
            gload_lds16(&kb[(key0 + row) * 64 + ksrc],
                        &lds_k[(p * 32 + wv * 8) * 64]);
        }
#pragma unroll
        for (int i = 0; i < 8; ++i) {
            unsigned int w = (unsigned int)(unsigned short)v0[i]
                           | ((unsigned int)(unsigned short)v1[i] << 16);
            *(unsigned int*)&lds_vt[(seg * 8 + i) * 74 + pos0] = w;
        }
        __syncthreads();

        bf16x8 kf[4][2];
#pragma unroll
        for (int kc = 0; kc < 4; ++kc)
#pragma unroll
            for (int h2 = 0; h2 < 2; ++h2)
                kf[kc][h2] = *(bf16x8*)
                    &lds_k[(kc * 16 + l15) * 64 + (((h2 * 4 + quad) ^ kswz) * 8)];

        union { bf16x8 v; unsigned int u[4]; } pfr[2][2];
#pragma unroll
        for (int qt = 0; qt < 2; ++qt) {
#pragma unroll
            for (int kc = 0; kc < 4; ++kc) {
                fp32x4 s;
#pragma unroll
                for (int r = 0; r < 4; ++r) s[r] = 0.f;
                s = MFMA16(kf[kc][0], qf[qt][0], s);
                s = MFMA16(kf[kc][1], qf[qt][1], s);
                fp32x4 p;
#pragma unroll
                for (int r = 0; r < 4; ++r) {
                    p[r] = __builtin_amdgcn_exp2f(s[r] * SCL2E);
                    rs4[qt][r] += p[r];
                }
                pfr[qt][kc >> 1].u[(kc & 1) * 2 + 0] = cvt_pk_bf16(p[0], p[1]);
                pfr[qt][kc >> 1].u[(kc & 1) * 2 + 1] = cvt_pk_bf16(p[2], p[3]);
            }
        }

#pragma unroll
        for (int g = 0; g < 4; ++g)
#pragma unroll
            for (int ks = 0; ks < 2; ++ks) {
                bf16x8 vf = *(bf16x8*)
                    &lds_vt[(g * 16 + l15) * 74 + ks * 32 + quad * 8];
#pragma unroll
                for (int qt = 0; qt < 2; ++qt)
                    O[qt][g] = MFMA16(pfr[qt][ks].v, vf, O[qt][g]);
            }
    }

    const int b = bh >> 4, h = bh & 15;
#pragma unroll
    for (int qt = 0; qt < 2; ++qt) {
        float t = (rs4[qt][0] + rs4[qt][1]) + (rs4[qt][2] + rs4[qt][3]);
        t += __shfl_xor(t, 16);
        t += __shfl_xor(t, 32);
#pragma unroll
        for (int r = 0; r < 4; ++r) {
            float tot = __shfl(t, quad * 4 + r);
            float inv = 1.f / tot;
            int qq  = q0 + qt * 16 + quad * 4 + r;
            int row = b * 2048 + qq;
#pragma unroll
            for (int g = 0; g < 4; ++g) {
                int col = h * 64 + g * 16 + l15;
                ctx[row * 1024 + col] = f2bf(O[qt][g][r] * inv);
            }
        }
    }
}

extern "C" void kernel_launch(void* const* d_in, const int* in_sizes, int n_in,
                              void* d_out, int out_size, void* d_ws, size_t ws_size,
                              hipStream_t stream) {
    const float* Q  = (const float*)d_in[0];
    const float* K  = (const float*)d_in[1];
    const float* V  = (const float*)d_in[2];
    const float* Wq = (const float*)d_in[3];
    const float* bq = (const float*)d_in[4];
    const float* Wk = (const float*)d_in[5];
    const float* bk = (const float*)d_in[6];
    const float* Wv = (const float*)d_in[7];
    const float* bv = (const float*)d_in[8];
    const float* Wo = (const float*)d_in[9];
    const float* bo = (const float*)d_in[10];

    const size_t NEL = 4096ull * 1024ull;
    // ws base: WbT (4M shorts) | vbuf (4M) | cbuf (4M) = 24 MB.
    // Extended (40 MB): + xq | xk; xv aliases cbuf (cbuf only written by
    // attention, after gemm1 has consumed xv -- lifetime-disjoint).
    short* wbt  = (short*)d_ws;
    short* vbuf = wbt + 4 * 1024 * 1024;
    short* cbuf = vbuf + NEL;
    short* xq   = cbuf + NEL;
    short* xk   = xq + NEL;
    short* xv   = cbuf;
    // q/k bf16 intermediates borrow d_out (consumed before final GEMM writes)
    short* qbuf = (short*)d_out;
    short* kbuf = (short*)d_out + NEL;

    const bool big_ws = ws_size >= (40ull << 20);

    dim3 blk(256);
    hipLaunchKernelGGL(transpose_w, dim3(16, 16, 4), blk, 0, stream,
                       Wq, Wk, Wv, Wo, wbt);

    GemmArgs g1;
    g1.W = wbt;
    g1.bias[0] = bq; g1.bias[1] = bk; g1.bias[2] = bv;
    g1.out[0] = qbuf; g1.out[1] = kbuf; g1.out[2] = vbuf;
    if (big_ws) {
        hipLaunchKernelGGL(convert_x, dim3(512, 3), blk, 0, stream,
                           Q, K, V, xq, xk, xv);
        g1.X[0] = xq; g1.X[1] = xk; g1.X[2] = xv;
        hipLaunchKernelGGL((gemm128<false, true>), dim3(8, 32, 3), blk, 0,
                           stream, g1);
    } else {
        g1.X[0] = Q;  g1.X[1] = K;  g1.X[2] = V;
        hipLaunchKernelGGL((gemm128<true, true>), dim3(8, 32, 3), blk, 0,
                           stream, g1);
    }

    hipLaunchKernelGGL(attention128, dim3(16, 32), blk, 0, stream,
                       qbuf, kbuf, vbuf, cbuf);

    GemmArgs g2;
    g2.X[0] = cbuf; g2.X[1] = cbuf; g2.X[2] = cbuf;
    g2.W = wbt + 3ull * 1024 * 1024;
    g2.bias[0] = bo; g2.bias[1] = bo; g2.bias[2] = bo;
    g2.out[0] = d_out; g2.out[1] = d_out; g2.out[2] = d_out;
    hipLaunchKernelGGL((gemm128<false, false>), dim3(8, 32, 1), blk, 0, stream, g2);
}